// Round 3
// baseline (1266.548 us; speedup 1.0000x reference)
//
#include <hip/hip_runtime.h>
#include <cmath>

// LAGCNII round 5: occupancy attack. Rounds 3-4 pinned layer_fused at 18% occupancy
// (= 1 block/CU, 4 serial rounds of 782 blocks) regardless of 88 vs 67.6KB LDS.
// Fix: 64-row tile -> As = 33.8KB, wave tile 32x64, VGPR<=64 via launch_bounds(512,8)
// => 4 blocks/CU = 32 waves/CU. Gather latency hidden by TLP.
// ws: h0|h|x bf16 (153.6MB) + bf16 W^T (1.2MB) + CSR ints (~2.4MB).

#define N_NODES 100000
#define N_EDGES 300000
#define DIN 256
#define CHN 256
#define DHID 128
#define NCLASS 40
#define NLAYER 8
#define SCAN_NB 98  // ceil(100000 / 1024)

typedef short bf16x8 __attribute__((ext_vector_type(8)));
typedef float f32x4 __attribute__((ext_vector_type(4)));

__device__ inline short f2bf(float f) {
  unsigned u = __float_as_uint(f);
  unsigned r = (u + 0x7FFFu + ((u >> 16) & 1u)) >> 16;
  return (short)r;
}
__device__ inline float bf2f(short s) {
  return __uint_as_float(((unsigned)(unsigned short)s) << 16);
}

// ---------------- CSR build (by dst) ----------------
__global__ void hist_kernel(const int* __restrict__ dst, int* __restrict__ cnt) {
  int e = blockIdx.x * 256 + threadIdx.x;
  if (e < N_EDGES) atomicAdd(&cnt[dst[e]], 1);
}

// per-block exclusive scan of 1024 values (256 thr x 4), block totals to bsums
__global__ __launch_bounds__(256) void bscan1(const int* __restrict__ cnt,
                                              int* __restrict__ rowp,
                                              int* __restrict__ bsums) {
  int tid = threadIdx.x;
  int base = blockIdx.x * 1024 + tid * 4;
  int v0 = 0, v1 = 0, v2 = 0, v3 = 0;
  if (base + 3 < N_NODES) {
    int4 v = *(const int4*)(cnt + base);
    v0 = v.x; v1 = v.y; v2 = v.z; v3 = v.w;
  } else {
    if (base + 0 < N_NODES) v0 = cnt[base + 0];
    if (base + 1 < N_NODES) v1 = cnt[base + 1];
    if (base + 2 < N_NODES) v2 = cnt[base + 2];
    if (base + 3 < N_NODES) v3 = cnt[base + 3];
  }
  int t = v0 + v1 + v2 + v3;
  int lane = tid & 63;
  int incl = t;
#pragma unroll
  for (int off = 1; off < 64; off <<= 1) {
    int x = __shfl_up(incl, off, 64);
    if (lane >= off) incl += x;
  }
  __shared__ int wsum[4];
  int wave = tid >> 6;
  if (lane == 63) wsum[wave] = incl;
  __syncthreads();
  int woff = 0;
  for (int w = 0; w < wave; w++) woff += wsum[w];
  int excl = woff + incl - t;
  int e0 = excl, e1 = e0 + v0, e2 = e1 + v1, e3 = e2 + v2;
  if (base + 0 < N_NODES) rowp[base + 0] = e0;
  if (base + 1 < N_NODES) rowp[base + 1] = e1;
  if (base + 2 < N_NODES) rowp[base + 2] = e2;
  if (base + 3 < N_NODES) rowp[base + 3] = e3;
  if (tid == 255) bsums[blockIdx.x] = woff + incl;
}

__global__ void bscan2(int* __restrict__ bsums, int* __restrict__ rowp) {
  if (threadIdx.x == 0 && blockIdx.x == 0) {
    int s = 0;
    for (int i = 0; i < SCAN_NB; i++) {
      int v = bsums[i];
      bsums[i] = s;
      s += v;
    }
    rowp[N_NODES] = s;
  }
}

__global__ __launch_bounds__(256) void bscan3(int* __restrict__ rowp,
                                              int* __restrict__ fill,
                                              const int* __restrict__ bsums) {
  int base = blockIdx.x * 1024 + threadIdx.x * 4;
  int off = bsums[blockIdx.x];
#pragma unroll
  for (int j = 0; j < 4; j++) {
    int i = base + j;
    if (i < N_NODES) {
      int p = rowp[i] + off;
      rowp[i] = p;
      fill[i] = p;
    }
  }
}

__global__ void scatter_kernel(const int* __restrict__ src, const int* __restrict__ dst,
                               int* __restrict__ fill, int* __restrict__ col) {
  int e = blockIdx.x * 256 + threadIdx.x;
  if (e < N_EDGES) {
    int p = atomicAdd(&fill[dst[e]], 1);
    col[p] = src[e];
  }
}

// ---------------- weight prep: bf16 transposed weights ----------------
__global__ void prep_w_kernel(const float* __restrict__ lw, const float* __restrict__ gw,
                              short* __restrict__ linT, short* __restrict__ gcnT) {
  int i = blockIdx.x * 256 + threadIdx.x;
  if (i < 2 * 128 * 256) {
    int v = i >> 15;
    int rem = i & 32767;
    int n = rem >> 8;
    int k = rem & 255;
    linT[i] = f2bf(lw[v * (DIN * DHID) + k * DHID + n]);
  }
  int j = i - 2 * 128 * 256;
  if (j >= 0 && j < 8 * 256 * 256) {
    int l = j >> 16;
    int rem = j & 65535;
    int n = rem >> 8;
    int k = rem & 255;
    gcnT[j] = f2bf(gw[l * (CHN * CHN) + k * CHN + n]);
  }
}

// ---------------- lin: h0[:, v*128+n] = relu(Xv @ Wv + bv), bf16 out ----------------
__global__ __launch_bounds__(256) void lin_mfma_kernel(const float* __restrict__ x0,
                                                       const float* __restrict__ x1,
                                                       const short* __restrict__ linT,
                                                       const float* __restrict__ lb,
                                                       short* __restrict__ h0) {
  const int view = blockIdx.y;
  const float* __restrict__ X = view ? x1 : x0;
  const short* __restrict__ Wt = linT + view * (DHID * DIN);  // [n][k]
  const int row0 = blockIdx.x * 128;
  __shared__ short As[128 * 40];
  __shared__ short Bs[128 * 40];
  const int tid = threadIdx.x;
  const int lane = tid & 63, wave = tid >> 6;
  const int quad = lane >> 4, mrem = lane & 15;
  const int wrow = (wave & 1) * 64, wcol = (wave >> 1) * 64;

  f32x4 acc[4][4];
#pragma unroll
  for (int i = 0; i < 4; i++)
#pragma unroll
    for (int j = 0; j < 4; j++) acc[i][j] = (f32x4){0.f, 0.f, 0.f, 0.f};

  const int sr = tid >> 1;
  const int sk = (tid & 1) * 16;
  for (int k0 = 0; k0 < DIN; k0 += 32) {
    {
      int gr = row0 + sr;
      float v[16];
      if (gr < N_NODES) {
        const float* p = X + (size_t)gr * DIN + k0 + sk;
        *(float4*)(v + 0) = *(const float4*)(p + 0);
        *(float4*)(v + 4) = *(const float4*)(p + 4);
        *(float4*)(v + 8) = *(const float4*)(p + 8);
        *(float4*)(v + 12) = *(const float4*)(p + 12);
      } else {
#pragma unroll
        for (int i = 0; i < 16; i++) v[i] = 0.f;
      }
      short s[16];
#pragma unroll
      for (int i = 0; i < 16; i++) s[i] = f2bf(v[i]);
      *(bf16x8*)&As[sr * 40 + sk] = *(bf16x8*)(s);
      *(bf16x8*)&As[sr * 40 + sk + 8] = *(bf16x8*)(s + 8);
    }
    {
      const short* p = Wt + (size_t)sr * DIN + k0 + sk;
      bf16x8 b0 = *(const bf16x8*)p;
      bf16x8 b1 = *(const bf16x8*)(p + 8);
      *(bf16x8*)&Bs[sr * 40 + sk] = b0;
      *(bf16x8*)&Bs[sr * 40 + sk + 8] = b1;
    }
    __syncthreads();
    bf16x8 af[4], bfr[4];
#pragma unroll
    for (int i = 0; i < 4; i++) af[i] = *(const bf16x8*)&As[(wrow + i * 16 + mrem) * 40 + quad * 8];
#pragma unroll
    for (int j = 0; j < 4; j++) bfr[j] = *(const bf16x8*)&Bs[(wcol + j * 16 + mrem) * 40 + quad * 8];
#pragma unroll
    for (int i = 0; i < 4; i++)
#pragma unroll
      for (int j = 0; j < 4; j++)
        acc[i][j] = __builtin_amdgcn_mfma_f32_16x16x32_bf16(af[i], bfr[j], acc[i][j], 0, 0, 0);
    __syncthreads();
  }
#pragma unroll
  for (int i = 0; i < 4; i++) {
#pragma unroll
    for (int j = 0; j < 4; j++) {
      int lcol = wcol + j * 16 + mrem;
      float bb = lb[view * DHID + lcol];
#pragma unroll
      for (int r = 0; r < 4; r++) {
        int grow = row0 + wrow + i * 16 + quad * 4 + r;
        if (grow < N_NODES)
          h0[(size_t)grow * CHN + view * DHID + lcol] = f2bf(fmaxf(acc[i][j][r] + bb, 0.f));
      }
    }
  }
}

// ---------------- fused layer: agg + residual + GEMM + identity map + relu --------
// 512 threads, tile = 64 rows x 256 cols. LDS = 33.8KB, VGPR<=64 => 4 blocks/CU
// (32 waves/CU). Phase 1: x tile -> LDS, 2 concurrent row-chains/thread with col
// prefetch. Phase 2: barrier-free k-loop, A from LDS, B direct from global (L2).
// Epilogue: residual x from LDS.
__global__ __launch_bounds__(512, 8) void layer_fused(const short* __restrict__ h,
                                                      const short* __restrict__ h0,
                                                      const int* __restrict__ rowp,
                                                      const int* __restrict__ col,
                                                      const short* __restrict__ Wt,  // [n][k]
                                                      short* __restrict__ out, float beta) {
  __shared__ short As[64 * 264];  // 33.8 KB
  const int tid = threadIdx.x;
  const int row0 = blockIdx.x * 64;

  // ---- Phase 1: build x tile in LDS, 2 concurrent row-chains per thread ----
  const int t16 = tid & 15;   // col group: 16 shorts at t16*16
  const int team = tid >> 4;  // 0..31; rows team, team+32

  float acc[2][16];
#pragma unroll
  for (int p = 0; p < 2; p++)
#pragma unroll
    for (int q = 0; q < 16; q++) acc[p][q] = 0.f;

  int begs[2], dcnt[2];
  int maxd = 0;
#pragma unroll
  for (int p = 0; p < 2; p++) {
    const int gr = row0 + p * 32 + team;
    if (gr < N_NODES) {
      begs[p] = rowp[gr];
      dcnt[p] = rowp[gr + 1] - begs[p];
    } else {
      begs[p] = 0;
      dcnt[p] = 0;
    }
    maxd = max(maxd, dcnt[p]);
  }

  int scur[2];
#pragma unroll
  for (int p = 0; p < 2; p++) scur[p] = (0 < dcnt[p]) ? col[begs[p]] : -1;

  for (int i = 0; i < maxd; ++i) {
    int snxt[2];
#pragma unroll
    for (int p = 0; p < 2; p++) snxt[p] = (i + 1 < dcnt[p]) ? col[begs[p] + i + 1] : -1;
#pragma unroll
    for (int p = 0; p < 2; p++) {
      const int s = scur[p];
      if (s >= 0) {
        const short* hp = h + (size_t)s * CHN + t16 * 16;
        bf16x8 v0 = *(const bf16x8*)hp;
        bf16x8 v1 = *(const bf16x8*)(hp + 8);
#pragma unroll
        for (int q = 0; q < 8; q++) {
          acc[p][q] += bf2f(v0[q]);
          acc[p][q + 8] += bf2f(v1[q]);
        }
      }
    }
#pragma unroll
    for (int p = 0; p < 2; p++) scur[p] = snxt[p];
  }

#pragma unroll
  for (int p = 0; p < 2; p++) {
    const int r = p * 32 + team;
    const int gr = row0 + r;
    if (gr < N_NODES) {
      const short* p0 = h0 + (size_t)gr * CHN + t16 * 16;
      bf16x8 r0 = *(const bf16x8*)p0;
      bf16x8 r1 = *(const bf16x8*)(p0 + 8);
      short o[16];
#pragma unroll
      for (int q = 0; q < 8; q++) {
        o[q] = f2bf(0.9f * acc[p][q] + 0.1f * bf2f(r0[q]));
        o[q + 8] = f2bf(0.9f * acc[p][q + 8] + 0.1f * bf2f(r1[q]));
      }
      *(bf16x8*)&As[r * 264 + t16 * 16] = *(bf16x8*)o;
      *(bf16x8*)&As[r * 264 + t16 * 16 + 8] = *(bf16x8*)(o + 8);
    } else {
      bf16x8 z = (bf16x8)(short)0;
      *(bf16x8*)&As[r * 264 + t16 * 16] = z;
      *(bf16x8*)&As[r * 264 + t16 * 16 + 8] = z;
    }
  }
  __syncthreads();

  // ---- Phase 2: barrier-free GEMM; wave tile 32x64; B direct from global (L2) ----
  const int lane = tid & 63, wave = tid >> 6;
  const int quad = lane >> 4, mrem = lane & 15;
  const int wrow = (wave >> 2) * 32;  // 0 / 32
  const int wcol = (wave & 3) * 64;   // 0 / 64 / 128 / 192
  f32x4 acc2[2][4];
#pragma unroll
  for (int i = 0; i < 2; i++)
#pragma unroll
    for (int j = 0; j < 4; j++) acc2[i][j] = (f32x4){0.f, 0.f, 0.f, 0.f};

  for (int k0 = 0; k0 < CHN; k0 += 32) {
    bf16x8 af[2], bfr[4];
#pragma unroll
    for (int j = 0; j < 4; j++)
      bfr[j] = *(const bf16x8*)(Wt + (size_t)(wcol + j * 16 + mrem) * CHN + k0 + quad * 8);
#pragma unroll
    for (int i = 0; i < 2; i++)
      af[i] = *(const bf16x8*)&As[(wrow + i * 16 + mrem) * 264 + k0 + quad * 8];
#pragma unroll
    for (int i = 0; i < 2; i++)
#pragma unroll
      for (int j = 0; j < 4; j++)
        acc2[i][j] = __builtin_amdgcn_mfma_f32_16x16x32_bf16(af[i], bfr[j], acc2[i][j], 0, 0, 0);
  }

  // ---- Epilogue: residual from LDS, write h ----
  const float omb = 1.f - beta;
#pragma unroll
  for (int i = 0; i < 2; i++) {
#pragma unroll
    for (int j = 0; j < 4; j++) {
      const int lcol = wcol + j * 16 + mrem;
#pragma unroll
      for (int r = 0; r < 4; r++) {
        const int lrow = wrow + i * 16 + quad * 4 + r;
        const int grow = row0 + lrow;
        if (grow < N_NODES) {
          float xv = bf2f(As[lrow * 264 + lcol]);
          out[(size_t)grow * CHN + lcol] = f2bf(fmaxf(omb * xv + beta * acc2[i][j][r], 0.f));
        }
      }
    }
  }
}

// ---------------- out: out = h @ Wo + bo  (M=100000, K=256, N=40) ----------------
__global__ __launch_bounds__(256) void out_kernel(const short* __restrict__ h,
                                                  const float* __restrict__ W,
                                                  const float* __restrict__ b,
                                                  float* __restrict__ out) {
  __shared__ float xs[32][260];
  __shared__ float ws[64][40];
  const int row0 = blockIdx.x * 32;
  const int tid = threadIdx.x;
  for (int f = tid; f < 1024; f += 256) {
    int r = f >> 5;
    int c = (f & 31) * 8;
    bf16x8 v = *(const bf16x8*)(h + (size_t)(row0 + r) * CHN + c);
    float t0[8];
#pragma unroll
    for (int q = 0; q < 8; q++) t0[q] = bf2f(v[q]);
    *(float4*)&xs[r][c] = *(float4*)(t0);
    *(float4*)&xs[r][c + 4] = *(float4*)(t0 + 4);
  }
  const int r = tid >> 3;
  const int cg = (tid & 7) * 5;
  float acc[5];
#pragma unroll
  for (int j = 0; j < 5; j++) acc[j] = b[cg + j];
  for (int k0 = 0; k0 < CHN; k0 += 64) {
    for (int i = tid; i < 64 * 40; i += 256) {
      int k = i / 40, c = i % 40;
      ws[k][c] = W[(size_t)(k0 + k) * NCLASS + c];
    }
    __syncthreads();
#pragma unroll 8
    for (int k = 0; k < 64; k++) {
      float xv = xs[r][k0 + k];
#pragma unroll
      for (int j = 0; j < 5; j++) acc[j] += xv * ws[k][cg + j];
    }
    __syncthreads();
  }
  float* op = out + (size_t)(row0 + r) * NCLASS + cg;
#pragma unroll
  for (int j = 0; j < 5; j++) op[j] = acc[j];
}

extern "C" void kernel_launch(void* const* d_in, const int* in_sizes, int n_in,
                              void* d_out, int out_size, void* d_ws, size_t ws_size,
                              hipStream_t stream) {
  const float* x0 = (const float*)d_in[0];
  const float* x1 = (const float*)d_in[1];
  const int* ei = (const int*)d_in[2];
  const float* lw = (const float*)d_in[3];
  const float* lb = (const float*)d_in[4];
  const float* gw = (const float*)d_in[5];
  const float* ow = (const float*)d_in[6];
  const float* ob = (const float*)d_in[7];
  float* outp = (float*)d_out;

  const size_t NC = (size_t)N_NODES * CHN;
  short* h0 = (short*)d_ws;
  short* hb = h0 + NC;
  short* xb = hb + NC;
  short* linT = xb + NC;                    // 153.6MB offset, 16B aligned
  short* gcnT = linT + 2 * DHID * DIN;      // +128KB
  int* cnt = (int*)(gcnT + 8 * CHN * CHN);  // +1MB
  int* rowp = cnt + N_NODES;
  int* fill = rowp + N_NODES + 1;
  int* col = fill + N_NODES;
  int* bsums = col + N_EDGES;

  const int* src = ei;
  const int* dst = ei + N_EDGES;

  hipMemsetAsync(cnt, 0, N_NODES * sizeof(int), stream);
  hist_kernel<<<(N_EDGES + 255) / 256, 256, 0, stream>>>(dst, cnt);
  bscan1<<<SCAN_NB, 256, 0, stream>>>(cnt, rowp, bsums);
  bscan2<<<1, 64, 0, stream>>>(bsums, rowp);
  bscan3<<<SCAN_NB, 256, 0, stream>>>(rowp, fill, bsums);
  scatter_kernel<<<(N_EDGES + 255) / 256, 256, 0, stream>>>(src, dst, fill, col);
  prep_w_kernel<<<(2 * 128 * 256 + 8 * 256 * 256 + 255) / 256, 256, 0, stream>>>(lw, gw, linT, gcnT);

  dim3 lg((N_NODES + 127) / 128, 2);
  lin_mfma_kernel<<<lg, 256, 0, stream>>>(x0, x1, linT, lb, h0);

  // layers: fused agg+gemm; h ping-pongs hb <-> xb (gather reads prev buffer,
  // kernel-launch boundary is the producer/consumer barrier)
  const short* hin = h0;
  for (int l = 0; l < NLAYER; ++l) {
    float beta = logf(0.5f / (float)(l + 1) + 1.0f);
    short* hout = (l & 1) ? xb : hb;
    layer_fused<<<(N_NODES + 63) / 64, 512, 0, stream>>>(hin, h0, rowp, col,
                                                         gcnT + (size_t)l * CHN * CHN,
                                                         hout, beta);
    hin = hout;
  }
  out_kernel<<<N_NODES / 32, 256, 0, stream>>>(hin, ow, ob, outp);
}

// Round 4
// 1135.227 us; speedup vs baseline: 1.1157x; 1.1157x over previous
//
#include <hip/hip_runtime.h>
#include <cmath>

// LAGCNII round 6:
//  (a) layer_fused: round-5's (512,8) bound forced VGPR=32 -> scratch spills
//      (WRITE_SIZE 50->144MB). Relax to (512,6): cap ~84 VGPR, 3 blocks/CU,
//      no spill. Occupancy stays high, spill traffic gone.
//  (b) lin_mfma_kernel: rewritten LDS-free + barrier-free. A-frags loaded
//      direct from global X (float4 x2 + in-register f2bf), B-frags direct
//      from L2-resident linT. Pure streaming MFMA, no __syncthreads.
// ws: h0|h|x bf16 (153.6MB) + bf16 W^T (1.2MB) + CSR ints (~2.4MB).

#define N_NODES 100000
#define N_EDGES 300000
#define DIN 256
#define CHN 256
#define DHID 128
#define NCLASS 40
#define NLAYER 8
#define SCAN_NB 98  // ceil(100000 / 1024)

typedef short bf16x8 __attribute__((ext_vector_type(8)));
typedef float f32x4 __attribute__((ext_vector_type(4)));

__device__ inline short f2bf(float f) {
  unsigned u = __float_as_uint(f);
  unsigned r = (u + 0x7FFFu + ((u >> 16) & 1u)) >> 16;
  return (short)r;
}
__device__ inline float bf2f(short s) {
  return __uint_as_float(((unsigned)(unsigned short)s) << 16);
}

// ---------------- CSR build (by dst) ----------------
__global__ void hist_kernel(const int* __restrict__ dst, int* __restrict__ cnt) {
  int e = blockIdx.x * 256 + threadIdx.x;
  if (e < N_EDGES) atomicAdd(&cnt[dst[e]], 1);
}

// per-block exclusive scan of 1024 values (256 thr x 4), block totals to bsums
__global__ __launch_bounds__(256) void bscan1(const int* __restrict__ cnt,
                                              int* __restrict__ rowp,
                                              int* __restrict__ bsums) {
  int tid = threadIdx.x;
  int base = blockIdx.x * 1024 + tid * 4;
  int v0 = 0, v1 = 0, v2 = 0, v3 = 0;
  if (base + 3 < N_NODES) {
    int4 v = *(const int4*)(cnt + base);
    v0 = v.x; v1 = v.y; v2 = v.z; v3 = v.w;
  } else {
    if (base + 0 < N_NODES) v0 = cnt[base + 0];
    if (base + 1 < N_NODES) v1 = cnt[base + 1];
    if (base + 2 < N_NODES) v2 = cnt[base + 2];
    if (base + 3 < N_NODES) v3 = cnt[base + 3];
  }
  int t = v0 + v1 + v2 + v3;
  int lane = tid & 63;
  int incl = t;
#pragma unroll
  for (int off = 1; off < 64; off <<= 1) {
    int x = __shfl_up(incl, off, 64);
    if (lane >= off) incl += x;
  }
  __shared__ int wsum[4];
  int wave = tid >> 6;
  if (lane == 63) wsum[wave] = incl;
  __syncthreads();
  int woff = 0;
  for (int w = 0; w < wave; w++) woff += wsum[w];
  int excl = woff + incl - t;
  int e0 = excl, e1 = e0 + v0, e2 = e1 + v1, e3 = e2 + v2;
  if (base + 0 < N_NODES) rowp[base + 0] = e0;
  if (base + 1 < N_NODES) rowp[base + 1] = e1;
  if (base + 2 < N_NODES) rowp[base + 2] = e2;
  if (base + 3 < N_NODES) rowp[base + 3] = e3;
  if (tid == 255) bsums[blockIdx.x] = woff + incl;
}

__global__ void bscan2(int* __restrict__ bsums, int* __restrict__ rowp) {
  if (threadIdx.x == 0 && blockIdx.x == 0) {
    int s = 0;
    for (int i = 0; i < SCAN_NB; i++) {
      int v = bsums[i];
      bsums[i] = s;
      s += v;
    }
    rowp[N_NODES] = s;
  }
}

__global__ __launch_bounds__(256) void bscan3(int* __restrict__ rowp,
                                              int* __restrict__ fill,
                                              const int* __restrict__ bsums) {
  int base = blockIdx.x * 1024 + threadIdx.x * 4;
  int off = bsums[blockIdx.x];
#pragma unroll
  for (int j = 0; j < 4; j++) {
    int i = base + j;
    if (i < N_NODES) {
      int p = rowp[i] + off;
      rowp[i] = p;
      fill[i] = p;
    }
  }
}

__global__ void scatter_kernel(const int* __restrict__ src, const int* __restrict__ dst,
                               int* __restrict__ fill, int* __restrict__ col) {
  int e = blockIdx.x * 256 + threadIdx.x;
  if (e < N_EDGES) {
    int p = atomicAdd(&fill[dst[e]], 1);
    col[p] = src[e];
  }
}

// ---------------- weight prep: bf16 transposed weights ----------------
__global__ void prep_w_kernel(const float* __restrict__ lw, const float* __restrict__ gw,
                              short* __restrict__ linT, short* __restrict__ gcnT) {
  int i = blockIdx.x * 256 + threadIdx.x;
  if (i < 2 * 128 * 256) {
    int v = i >> 15;
    int rem = i & 32767;
    int n = rem >> 8;
    int k = rem & 255;
    linT[i] = f2bf(lw[v * (DIN * DHID) + k * DHID + n]);
  }
  int j = i - 2 * 128 * 256;
  if (j >= 0 && j < 8 * 256 * 256) {
    int l = j >> 16;
    int rem = j & 65535;
    int n = rem >> 8;
    int k = rem & 255;
    gcnT[j] = f2bf(gw[l * (CHN * CHN) + k * CHN + n]);
  }
}

// ---------------- lin: h0[:, v*128+n] = relu(Xv @ Wv + bv), bf16 out ----------------
// LDS-free, barrier-free: A-frags direct from global X (f32 -> bf16 in register),
// B-frags direct from L2-resident linT. 4 waves cover 128x128 (2x2 of 64x64).
__global__ __launch_bounds__(256) void lin_mfma_kernel(const float* __restrict__ x0,
                                                       const float* __restrict__ x1,
                                                       const short* __restrict__ linT,
                                                       const float* __restrict__ lb,
                                                       short* __restrict__ h0) {
  const int view = blockIdx.y;
  const float* __restrict__ X = view ? x1 : x0;
  const short* __restrict__ Wt = linT + view * (DHID * DIN);  // [n][k]
  const int row0 = blockIdx.x * 128;
  const int tid = threadIdx.x;
  const int lane = tid & 63, wave = tid >> 6;
  const int quad = lane >> 4, mrem = lane & 15;
  const int wrow = (wave & 1) * 64, wcol = (wave >> 1) * 64;

  f32x4 acc[4][4];
#pragma unroll
  for (int i = 0; i < 4; i++)
#pragma unroll
    for (int j = 0; j < 4; j++) acc[i][j] = (f32x4){0.f, 0.f, 0.f, 0.f};

  for (int k0 = 0; k0 < DIN; k0 += 32) {
    bf16x8 af[4], bfr[4];
#pragma unroll
    for (int j = 0; j < 4; j++)
      bfr[j] = *(const bf16x8*)(Wt + (size_t)(wcol + j * 16 + mrem) * DIN + k0 + quad * 8);
#pragma unroll
    for (int i = 0; i < 4; i++) {
      const int gr = row0 + wrow + i * 16 + mrem;
      float v[8];
      if (gr < N_NODES) {
        const float* p = X + (size_t)gr * DIN + k0 + quad * 8;
        *(float4*)(v + 0) = *(const float4*)(p + 0);
        *(float4*)(v + 4) = *(const float4*)(p + 4);
      } else {
#pragma unroll
        for (int q = 0; q < 8; q++) v[q] = 0.f;
      }
      short s[8];
#pragma unroll
      for (int q = 0; q < 8; q++) s[q] = f2bf(v[q]);
      af[i] = *(const bf16x8*)s;
    }
#pragma unroll
    for (int i = 0; i < 4; i++)
#pragma unroll
      for (int j = 0; j < 4; j++)
        acc[i][j] = __builtin_amdgcn_mfma_f32_16x16x32_bf16(af[i], bfr[j], acc[i][j], 0, 0, 0);
  }
#pragma unroll
  for (int i = 0; i < 4; i++) {
#pragma unroll
    for (int j = 0; j < 4; j++) {
      int lcol = wcol + j * 16 + mrem;
      float bb = lb[view * DHID + lcol];
#pragma unroll
      for (int r = 0; r < 4; r++) {
        int grow = row0 + wrow + i * 16 + quad * 4 + r;
        if (grow < N_NODES)
          h0[(size_t)grow * CHN + view * DHID + lcol] = f2bf(fmaxf(acc[i][j][r] + bb, 0.f));
      }
    }
  }
}

// ---------------- fused layer: agg + residual + GEMM + identity map + relu --------
// 512 threads, tile = 64 rows x 256 cols. LDS = 33.8KB. launch_bounds(512,6):
// VGPR cap ~84 (no spill, round-5's (512,8) cap=64 forced scratch spills),
// 3 blocks/CU = 24 waves/CU. Phase 1: x tile -> LDS, 2 concurrent row-chains.
// Phase 2: barrier-free k-loop, A from LDS, B direct from global (L2).
__global__ __launch_bounds__(512, 6) void layer_fused(const short* __restrict__ h,
                                                      const short* __restrict__ h0,
                                                      const int* __restrict__ rowp,
                                                      const int* __restrict__ col,
                                                      const short* __restrict__ Wt,  // [n][k]
                                                      short* __restrict__ out, float beta) {
  __shared__ short As[64 * 264];  // 33.8 KB
  const int tid = threadIdx.x;
  const int row0 = blockIdx.x * 64;

  // ---- Phase 1: build x tile in LDS, 2 concurrent row-chains per thread ----
  const int t16 = tid & 15;   // col group: 16 shorts at t16*16
  const int team = tid >> 4;  // 0..31; rows team, team+32

  float acc[2][16];
#pragma unroll
  for (int p = 0; p < 2; p++)
#pragma unroll
    for (int q = 0; q < 16; q++) acc[p][q] = 0.f;

  int begs[2], dcnt[2];
  int maxd = 0;
#pragma unroll
  for (int p = 0; p < 2; p++) {
    const int gr = row0 + p * 32 + team;
    if (gr < N_NODES) {
      begs[p] = rowp[gr];
      dcnt[p] = rowp[gr + 1] - begs[p];
    } else {
      begs[p] = 0;
      dcnt[p] = 0;
    }
    maxd = max(maxd, dcnt[p]);
  }

  int scur[2];
#pragma unroll
  for (int p = 0; p < 2; p++) scur[p] = (0 < dcnt[p]) ? col[begs[p]] : -1;

  for (int i = 0; i < maxd; ++i) {
    int snxt[2];
#pragma unroll
    for (int p = 0; p < 2; p++) snxt[p] = (i + 1 < dcnt[p]) ? col[begs[p] + i + 1] : -1;
#pragma unroll
    for (int p = 0; p < 2; p++) {
      const int s = scur[p];
      if (s >= 0) {
        const short* hp = h + (size_t)s * CHN + t16 * 16;
        bf16x8 v0 = *(const bf16x8*)hp;
        bf16x8 v1 = *(const bf16x8*)(hp + 8);
#pragma unroll
        for (int q = 0; q < 8; q++) {
          acc[p][q] += bf2f(v0[q]);
          acc[p][q + 8] += bf2f(v1[q]);
        }
      }
    }
#pragma unroll
    for (int p = 0; p < 2; p++) scur[p] = snxt[p];
  }

#pragma unroll
  for (int p = 0; p < 2; p++) {
    const int r = p * 32 + team;
    const int gr = row0 + r;
    if (gr < N_NODES) {
      const short* p0 = h0 + (size_t)gr * CHN + t16 * 16;
      bf16x8 r0 = *(const bf16x8*)p0;
      bf16x8 r1 = *(const bf16x8*)(p0 + 8);
      short o[16];
#pragma unroll
      for (int q = 0; q < 8; q++) {
        o[q] = f2bf(0.9f * acc[p][q] + 0.1f * bf2f(r0[q]));
        o[q + 8] = f2bf(0.9f * acc[p][q + 8] + 0.1f * bf2f(r1[q]));
      }
      *(bf16x8*)&As[r * 264 + t16 * 16] = *(bf16x8*)o;
      *(bf16x8*)&As[r * 264 + t16 * 16 + 8] = *(bf16x8*)(o + 8);
    } else {
      bf16x8 z = (bf16x8)(short)0;
      *(bf16x8*)&As[r * 264 + t16 * 16] = z;
      *(bf16x8*)&As[r * 264 + t16 * 16 + 8] = z;
    }
  }
  __syncthreads();

  // ---- Phase 2: barrier-free GEMM; wave tile 32x64; B direct from global (L2) ----
  const int lane = tid & 63, wave = tid >> 6;
  const int quad = lane >> 4, mrem = lane & 15;
  const int wrow = (wave >> 2) * 32;  // 0 / 32
  const int wcol = (wave & 3) * 64;   // 0 / 64 / 128 / 192
  f32x4 acc2[2][4];
#pragma unroll
  for (int i = 0; i < 2; i++)
#pragma unroll
    for (int j = 0; j < 4; j++) acc2[i][j] = (f32x4){0.f, 0.f, 0.f, 0.f};

  for (int k0 = 0; k0 < CHN; k0 += 32) {
    bf16x8 af[2], bfr[4];
#pragma unroll
    for (int j = 0; j < 4; j++)
      bfr[j] = *(const bf16x8*)(Wt + (size_t)(wcol + j * 16 + mrem) * CHN + k0 + quad * 8);
#pragma unroll
    for (int i = 0; i < 2; i++)
      af[i] = *(const bf16x8*)&As[(wrow + i * 16 + mrem) * 264 + k0 + quad * 8];
#pragma unroll
    for (int i = 0; i < 2; i++)
#pragma unroll
      for (int j = 0; j < 4; j++)
        acc2[i][j] = __builtin_amdgcn_mfma_f32_16x16x32_bf16(af[i], bfr[j], acc2[i][j], 0, 0, 0);
  }

  // ---- Epilogue: residual from LDS, write h ----
  const float omb = 1.f - beta;
#pragma unroll
  for (int i = 0; i < 2; i++) {
#pragma unroll
    for (int j = 0; j < 4; j++) {
      const int lcol = wcol + j * 16 + mrem;
#pragma unroll
      for (int r = 0; r < 4; r++) {
        const int lrow = wrow + i * 16 + quad * 4 + r;
        const int grow = row0 + lrow;
        if (grow < N_NODES) {
          float xv = bf2f(As[lrow * 264 + lcol]);
          out[(size_t)grow * CHN + lcol] = f2bf(fmaxf(omb * xv + beta * acc2[i][j][r], 0.f));
        }
      }
    }
  }
}

// ---------------- out: out = h @ Wo + bo  (M=100000, K=256, N=40) ----------------
__global__ __launch_bounds__(256) void out_kernel(const short* __restrict__ h,
                                                  const float* __restrict__ W,
                                                  const float* __restrict__ b,
                                                  float* __restrict__ out) {
  __shared__ float xs[32][260];
  __shared__ float ws[64][40];
  const int row0 = blockIdx.x * 32;
  const int tid = threadIdx.x;
  for (int f = tid; f < 1024; f += 256) {
    int r = f >> 5;
    int c = (f & 31) * 8;
    bf16x8 v = *(const bf16x8*)(h + (size_t)(row0 + r) * CHN + c);
    float t0[8];
#pragma unroll
    for (int q = 0; q < 8; q++) t0[q] = bf2f(v[q]);
    *(float4*)&xs[r][c] = *(float4*)(t0);
    *(float4*)&xs[r][c + 4] = *(float4*)(t0 + 4);
  }
  const int r = tid >> 3;
  const int cg = (tid & 7) * 5;
  float acc[5];
#pragma unroll
  for (int j = 0; j < 5; j++) acc[j] = b[cg + j];
  for (int k0 = 0; k0 < CHN; k0 += 64) {
    for (int i = tid; i < 64 * 40; i += 256) {
      int k = i / 40, c = i % 40;
      ws[k][c] = W[(size_t)(k0 + k) * NCLASS + c];
    }
    __syncthreads();
#pragma unroll 8
    for (int k = 0; k < 64; k++) {
      float xv = xs[r][k0 + k];
#pragma unroll
      for (int j = 0; j < 5; j++) acc[j] += xv * ws[k][cg + j];
    }
    __syncthreads();
  }
  float* op = out + (size_t)(row0 + r) * NCLASS + cg;
#pragma unroll
  for (int j = 0; j < 5; j++) op[j] = acc[j];
}

extern "C" void kernel_launch(void* const* d_in, const int* in_sizes, int n_in,
                              void* d_out, int out_size, void* d_ws, size_t ws_size,
                              hipStream_t stream) {
  const float* x0 = (const float*)d_in[0];
  const float* x1 = (const float*)d_in[1];
  const int* ei = (const int*)d_in[2];
  const float* lw = (const float*)d_in[3];
  const float* lb = (const float*)d_in[4];
  const float* gw = (const float*)d_in[5];
  const float* ow = (const float*)d_in[6];
  const float* ob = (const float*)d_in[7];
  float* outp = (float*)d_out;

  const size_t NC = (size_t)N_NODES * CHN;
  short* h0 = (short*)d_ws;
  short* hb = h0 + NC;
  short* xb = hb + NC;
  short* linT = xb + NC;                    // 153.6MB offset, 16B aligned
  short* gcnT = linT + 2 * DHID * DIN;      // +128KB
  int* cnt = (int*)(gcnT + 8 * CHN * CHN);  // +1MB
  int* rowp = cnt + N_NODES;
  int* fill = rowp + N_NODES + 1;
  int* col = fill + N_NODES;
  int* bsums = col + N_EDGES;

  const int* src = ei;
  const int* dst = ei + N_EDGES;

  hipMemsetAsync(cnt, 0, N_NODES * sizeof(int), stream);
  hist_kernel<<<(N_EDGES + 255) / 256, 256, 0, stream>>>(dst, cnt);
  bscan1<<<SCAN_NB, 256, 0, stream>>>(cnt, rowp, bsums);
  bscan2<<<1, 64, 0, stream>>>(bsums, rowp);
  bscan3<<<SCAN_NB, 256, 0, stream>>>(rowp, fill, bsums);
  scatter_kernel<<<(N_EDGES + 255) / 256, 256, 0, stream>>>(src, dst, fill, col);
  prep_w_kernel<<<(2 * 128 * 256 + 8 * 256 * 256 + 255) / 256, 256, 0, stream>>>(lw, gw, linT, gcnT);

  dim3 lg((N_NODES + 127) / 128, 2);
  lin_mfma_kernel<<<lg, 256, 0, stream>>>(x0, x1, linT, lb, h0);

  // layers: fused agg+gemm; h ping-pongs hb <-> xb (gather reads prev buffer,
  // kernel-launch boundary is the producer/consumer barrier)
  const short* hin = h0;
  for (int l = 0; l < NLAYER; ++l) {
    float beta = logf(0.5f / (float)(l + 1) + 1.0f);
    short* hout = (l & 1) ? xb : hb;
    layer_fused<<<(N_NODES + 63) / 64, 512, 0, stream>>>(hin, h0, rowp, col,
                                                         gcnT + (size_t)l * CHN * CHN,
                                                         hout, beta);
    hin = hout;
  }
  out_kernel<<<N_NODES / 32, 256, 0, stream>>>(hin, ow, ob, outp);
}

// Round 5
// 995.408 us; speedup vs baseline: 1.2724x; 1.1405x over previous
//
#include <hip/hip_runtime.h>
#include <cmath>

// LAGCNII round 7:
//  (a) lin: waves now cover DISTINCT 64-row groups (block = 256 rows x 64 cols,
//      grid (391,4)); X read exactly once (was 2x). Still LDS-free/barrier-free.
//  (b) layer_fused gather: 32 lanes/row x 16B (1 load per edge per lane, was 2),
//      4 concurrent row-chains/thread, index prefetch, zero-fill accumulate.
//  (c) layer_fused GEMM: wave tile 64x32 (bfr[2]); each wave reads distinct W
//      cols -> W L2 traffic halved, fewer long-latency loads per k-step.
// ws: h0|h|x bf16 (153.6MB) + bf16 W^T (1.2MB) + CSR ints (~2.4MB).

#define N_NODES 100000
#define N_EDGES 300000
#define DIN 256
#define CHN 256
#define DHID 128
#define NCLASS 40
#define NLAYER 8
#define SCAN_NB 98  // ceil(100000 / 1024)

typedef short bf16x8 __attribute__((ext_vector_type(8)));
typedef float f32x4 __attribute__((ext_vector_type(4)));

__device__ inline short f2bf(float f) {
  unsigned u = __float_as_uint(f);
  unsigned r = (u + 0x7FFFu + ((u >> 16) & 1u)) >> 16;
  return (short)r;
}
__device__ inline float bf2f(short s) {
  return __uint_as_float(((unsigned)(unsigned short)s) << 16);
}

// ---------------- CSR build (by dst) ----------------
__global__ void hist_kernel(const int* __restrict__ dst, int* __restrict__ cnt) {
  int e = blockIdx.x * 256 + threadIdx.x;
  if (e < N_EDGES) atomicAdd(&cnt[dst[e]], 1);
}

// per-block exclusive scan of 1024 values (256 thr x 4), block totals to bsums
__global__ __launch_bounds__(256) void bscan1(const int* __restrict__ cnt,
                                              int* __restrict__ rowp,
                                              int* __restrict__ bsums) {
  int tid = threadIdx.x;
  int base = blockIdx.x * 1024 + tid * 4;
  int v0 = 0, v1 = 0, v2 = 0, v3 = 0;
  if (base + 3 < N_NODES) {
    int4 v = *(const int4*)(cnt + base);
    v0 = v.x; v1 = v.y; v2 = v.z; v3 = v.w;
  } else {
    if (base + 0 < N_NODES) v0 = cnt[base + 0];
    if (base + 1 < N_NODES) v1 = cnt[base + 1];
    if (base + 2 < N_NODES) v2 = cnt[base + 2];
    if (base + 3 < N_NODES) v3 = cnt[base + 3];
  }
  int t = v0 + v1 + v2 + v3;
  int lane = tid & 63;
  int incl = t;
#pragma unroll
  for (int off = 1; off < 64; off <<= 1) {
    int x = __shfl_up(incl, off, 64);
    if (lane >= off) incl += x;
  }
  __shared__ int wsum[4];
  int wave = tid >> 6;
  if (lane == 63) wsum[wave] = incl;
  __syncthreads();
  int woff = 0;
  for (int w = 0; w < wave; w++) woff += wsum[w];
  int excl = woff + incl - t;
  int e0 = excl, e1 = e0 + v0, e2 = e1 + v1, e3 = e2 + v2;
  if (base + 0 < N_NODES) rowp[base + 0] = e0;
  if (base + 1 < N_NODES) rowp[base + 1] = e1;
  if (base + 2 < N_NODES) rowp[base + 2] = e2;
  if (base + 3 < N_NODES) rowp[base + 3] = e3;
  if (tid == 255) bsums[blockIdx.x] = woff + incl;
}

__global__ void bscan2(int* __restrict__ bsums, int* __restrict__ rowp) {
  if (threadIdx.x == 0 && blockIdx.x == 0) {
    int s = 0;
    for (int i = 0; i < SCAN_NB; i++) {
      int v = bsums[i];
      bsums[i] = s;
      s += v;
    }
    rowp[N_NODES] = s;
  }
}

__global__ __launch_bounds__(256) void bscan3(int* __restrict__ rowp,
                                              int* __restrict__ fill,
                                              const int* __restrict__ bsums) {
  int base = blockIdx.x * 1024 + threadIdx.x * 4;
  int off = bsums[blockIdx.x];
#pragma unroll
  for (int j = 0; j < 4; j++) {
    int i = base + j;
    if (i < N_NODES) {
      int p = rowp[i] + off;
      rowp[i] = p;
      fill[i] = p;
    }
  }
}

__global__ void scatter_kernel(const int* __restrict__ src, const int* __restrict__ dst,
                               int* __restrict__ fill, int* __restrict__ col) {
  int e = blockIdx.x * 256 + threadIdx.x;
  if (e < N_EDGES) {
    int p = atomicAdd(&fill[dst[e]], 1);
    col[p] = src[e];
  }
}

// ---------------- weight prep: bf16 transposed weights ----------------
__global__ void prep_w_kernel(const float* __restrict__ lw, const float* __restrict__ gw,
                              short* __restrict__ linT, short* __restrict__ gcnT) {
  int i = blockIdx.x * 256 + threadIdx.x;
  if (i < 2 * 128 * 256) {
    int v = i >> 15;
    int rem = i & 32767;
    int n = rem >> 8;
    int k = rem & 255;
    linT[i] = f2bf(lw[v * (DIN * DHID) + k * DHID + n]);
  }
  int j = i - 2 * 128 * 256;
  if (j >= 0 && j < 8 * 256 * 256) {
    int l = j >> 16;
    int rem = j & 65535;
    int n = rem >> 8;
    int k = rem & 255;
    gcnT[j] = f2bf(gw[l * (CHN * CHN) + k * CHN + n]);
  }
}

// ---------------- lin: h0[:, v*128+n] = relu(Xv @ Wv + bv), bf16 out ----------------
// LDS-free, barrier-free. Block = 256 rows x 64 cols; 4 waves on DISTINCT 64-row
// groups (X read once). grid (391, 4): y = view*2 + colhalf.
__global__ __launch_bounds__(256) void lin_mfma_kernel(const float* __restrict__ x0,
                                                       const float* __restrict__ x1,
                                                       const short* __restrict__ linT,
                                                       const float* __restrict__ lb,
                                                       short* __restrict__ h0) {
  const int y = blockIdx.y;  // 0..3
  const int view = y >> 1;
  const float* __restrict__ X = view ? x1 : x0;
  const short* __restrict__ Wt = linT + view * (DHID * DIN);  // [n][k]
  const int wcol = (y & 1) * 64;
  const int tid = threadIdx.x;
  const int lane = tid & 63, wave = tid >> 6;
  const int quad = lane >> 4, mrem = lane & 15;
  const int row0 = blockIdx.x * 256 + wave * 64;

  f32x4 acc[4][4];
#pragma unroll
  for (int i = 0; i < 4; i++)
#pragma unroll
    for (int j = 0; j < 4; j++) acc[i][j] = (f32x4){0.f, 0.f, 0.f, 0.f};

  for (int k0 = 0; k0 < DIN; k0 += 32) {
    bf16x8 af[4], bfr[4];
#pragma unroll
    for (int j = 0; j < 4; j++)
      bfr[j] = *(const bf16x8*)(Wt + (size_t)(wcol + j * 16 + mrem) * DIN + k0 + quad * 8);
#pragma unroll
    for (int i = 0; i < 4; i++) {
      const int gr = row0 + i * 16 + mrem;
      float v[8];
      if (gr < N_NODES) {
        const float* p = X + (size_t)gr * DIN + k0 + quad * 8;
        *(float4*)(v + 0) = *(const float4*)(p + 0);
        *(float4*)(v + 4) = *(const float4*)(p + 4);
      } else {
#pragma unroll
        for (int q = 0; q < 8; q++) v[q] = 0.f;
      }
      short s[8];
#pragma unroll
      for (int q = 0; q < 8; q++) s[q] = f2bf(v[q]);
      af[i] = *(const bf16x8*)s;
    }
#pragma unroll
    for (int i = 0; i < 4; i++)
#pragma unroll
      for (int j = 0; j < 4; j++)
        acc[i][j] = __builtin_amdgcn_mfma_f32_16x16x32_bf16(af[i], bfr[j], acc[i][j], 0, 0, 0);
  }
#pragma unroll
  for (int i = 0; i < 4; i++) {
#pragma unroll
    for (int j = 0; j < 4; j++) {
      int lcol = wcol + j * 16 + mrem;
      float bb = lb[view * DHID + lcol];
#pragma unroll
      for (int r = 0; r < 4; r++) {
        int grow = row0 + i * 16 + quad * 4 + r;
        if (grow < N_NODES)
          h0[(size_t)grow * CHN + view * DHID + lcol] = f2bf(fmaxf(acc[i][j][r] + bb, 0.f));
      }
    }
  }
}

// ---------------- fused layer: agg + residual + GEMM + identity map + relu --------
// 512 threads, tile = 64 rows x 256 cols, LDS = As only (33.8KB), (512,6).
// Phase 1: 32 lanes/row x 16B; 4 concurrent row-chains/thread; col-index
//          prefetched one edge ahead; exhausted chains accumulate zero vectors.
// Phase 2: barrier-free k-loop; wave tile 64 rows x 32 cols (bfr[2]) -> each
//          wave reads DISTINCT W cols (no duplication). A from LDS.
// Epilogue: residual x from LDS.
__global__ __launch_bounds__(512, 6) void layer_fused(const short* __restrict__ h,
                                                      const short* __restrict__ h0,
                                                      const int* __restrict__ rowp,
                                                      const int* __restrict__ col,
                                                      const short* __restrict__ Wt,  // [n][k]
                                                      short* __restrict__ out, float beta) {
  __shared__ short As[64 * 264];  // 33.8 KB
  const int tid = threadIdx.x;
  const int row0 = blockIdx.x * 64;

  // ---- Phase 1: gather; 32 lanes/row, 16B/lane, 4 chains/thread ----
  const int c8 = (tid & 31) * 8;  // col offset (shorts); 32 lanes x 8 = 256
  const int rb = tid >> 5;        // 0..15; rows rb, rb+16, rb+32, rb+48

  float acc[4][8];
#pragma unroll
  for (int p = 0; p < 4; p++)
#pragma unroll
    for (int q = 0; q < 8; q++) acc[p][q] = 0.f;

  int beg[4], cnt[4];
#pragma unroll
  for (int p = 0; p < 4; p++) {
    const int gr = row0 + rb + p * 16;
    if (gr < N_NODES) {
      beg[p] = rowp[gr];
      cnt[p] = rowp[gr + 1] - beg[p];
    } else {
      beg[p] = 0;
      cnt[p] = 0;
    }
  }
  const int maxd = max(max(cnt[0], cnt[1]), max(cnt[2], cnt[3]));

  int scur[4];
#pragma unroll
  for (int p = 0; p < 4; p++) scur[p] = (cnt[p] > 0) ? col[beg[p]] : -1;

  for (int i = 0; i < maxd; ++i) {
    int snxt[4];
#pragma unroll
    for (int p = 0; p < 4; p++) snxt[p] = (i + 1 < cnt[p]) ? col[beg[p] + i + 1] : -1;
    bf16x8 v[4];
#pragma unroll
    for (int p = 0; p < 4; p++)
      v[p] = (scur[p] >= 0) ? *(const bf16x8*)(h + (size_t)scur[p] * CHN + c8)
                            : (bf16x8)(short)0;
#pragma unroll
    for (int p = 0; p < 4; p++)
#pragma unroll
      for (int q = 0; q < 8; q++) acc[p][q] += bf2f(v[p][q]);
#pragma unroll
    for (int p = 0; p < 4; p++) scur[p] = snxt[p];
  }

#pragma unroll
  for (int p = 0; p < 4; p++) {
    const int r = rb + p * 16;
    const int gr = row0 + r;
    short o[8];
    if (gr < N_NODES) {
      bf16x8 r0 = *(const bf16x8*)(h0 + (size_t)gr * CHN + c8);
#pragma unroll
      for (int q = 0; q < 8; q++) o[q] = f2bf(0.9f * acc[p][q] + 0.1f * bf2f(r0[q]));
    } else {
#pragma unroll
      for (int q = 0; q < 8; q++) o[q] = 0;
    }
    *(bf16x8*)&As[r * 264 + c8] = *(bf16x8*)o;
  }
  __syncthreads();

  // ---- Phase 2: barrier-free GEMM; wave tile 64 rows x 32 cols ----
  const int lane = tid & 63, wave = tid >> 6;
  const int quad = lane >> 4, mrem = lane & 15;
  const int wcol = wave * 32;  // 8 waves x 32 = 256 cols, all distinct
  f32x4 acc2[4][2];
#pragma unroll
  for (int i = 0; i < 4; i++)
#pragma unroll
    for (int j = 0; j < 2; j++) acc2[i][j] = (f32x4){0.f, 0.f, 0.f, 0.f};

  for (int k0 = 0; k0 < CHN; k0 += 32) {
    bf16x8 af[4], bfr[2];
#pragma unroll
    for (int j = 0; j < 2; j++)
      bfr[j] = *(const bf16x8*)(Wt + (size_t)(wcol + j * 16 + mrem) * CHN + k0 + quad * 8);
#pragma unroll
    for (int i = 0; i < 4; i++)
      af[i] = *(const bf16x8*)&As[(i * 16 + mrem) * 264 + k0 + quad * 8];
#pragma unroll
    for (int i = 0; i < 4; i++)
#pragma unroll
      for (int j = 0; j < 2; j++)
        acc2[i][j] = __builtin_amdgcn_mfma_f32_16x16x32_bf16(af[i], bfr[j], acc2[i][j], 0, 0, 0);
  }

  // ---- Epilogue: residual from LDS, write h ----
  const float omb = 1.f - beta;
#pragma unroll
  for (int i = 0; i < 4; i++) {
#pragma unroll
    for (int j = 0; j < 2; j++) {
      const int lcol = wcol + j * 16 + mrem;
#pragma unroll
      for (int r = 0; r < 4; r++) {
        const int lrow = i * 16 + quad * 4 + r;
        const int grow = row0 + lrow;
        if (grow < N_NODES) {
          float xv = bf2f(As[lrow * 264 + lcol]);
          out[(size_t)grow * CHN + lcol] = f2bf(fmaxf(omb * xv + beta * acc2[i][j][r], 0.f));
        }
      }
    }
  }
}

// ---------------- out: out = h @ Wo + bo  (M=100000, K=256, N=40) ----------------
__global__ __launch_bounds__(256) void out_kernel(const short* __restrict__ h,
                                                  const float* __restrict__ W,
                                                  const float* __restrict__ b,
                                                  float* __restrict__ out) {
  __shared__ float xs[32][260];
  __shared__ float ws[64][40];
  const int row0 = blockIdx.x * 32;
  const int tid = threadIdx.x;
  for (int f = tid; f < 1024; f += 256) {
    int r = f >> 5;
    int c = (f & 31) * 8;
    bf16x8 v = *(const bf16x8*)(h + (size_t)(row0 + r) * CHN + c);
    float t0[8];
#pragma unroll
    for (int q = 0; q < 8; q++) t0[q] = bf2f(v[q]);
    *(float4*)&xs[r][c] = *(float4*)(t0);
    *(float4*)&xs[r][c + 4] = *(float4*)(t0 + 4);
  }
  const int r = tid >> 3;
  const int cg = (tid & 7) * 5;
  float acc[5];
#pragma unroll
  for (int j = 0; j < 5; j++) acc[j] = b[cg + j];
  for (int k0 = 0; k0 < CHN; k0 += 64) {
    for (int i = tid; i < 64 * 40; i += 256) {
      int k = i / 40, c = i % 40;
      ws[k][c] = W[(size_t)(k0 + k) * NCLASS + c];
    }
    __syncthreads();
#pragma unroll 8
    for (int k = 0; k < 64; k++) {
      float xv = xs[r][k0 + k];
#pragma unroll
      for (int j = 0; j < 5; j++) acc[j] += xv * ws[k][cg + j];
    }
    __syncthreads();
  }
  float* op = out + (size_t)(row0 + r) * NCLASS + cg;
#pragma unroll
  for (int j = 0; j < 5; j++) op[j] = acc[j];
}

extern "C" void kernel_launch(void* const* d_in, const int* in_sizes, int n_in,
                              void* d_out, int out_size, void* d_ws, size_t ws_size,
                              hipStream_t stream) {
  const float* x0 = (const float*)d_in[0];
  const float* x1 = (const float*)d_in[1];
  const int* ei = (const int*)d_in[2];
  const float* lw = (const float*)d_in[3];
  const float* lb = (const float*)d_in[4];
  const float* gw = (const float*)d_in[5];
  const float* ow = (const float*)d_in[6];
  const float* ob = (const float*)d_in[7];
  float* outp = (float*)d_out;

  const size_t NC = (size_t)N_NODES * CHN;
  short* h0 = (short*)d_ws;
  short* hb = h0 + NC;
  short* xb = hb + NC;
  short* linT = xb + NC;                    // 153.6MB offset, 16B aligned
  short* gcnT = linT + 2 * DHID * DIN;      // +128KB
  int* cnt = (int*)(gcnT + 8 * CHN * CHN);  // +1MB
  int* rowp = cnt + N_NODES;
  int* fill = rowp + N_NODES + 1;
  int* col = fill + N_NODES;
  int* bsums = col + N_EDGES;

  const int* src = ei;
  const int* dst = ei + N_EDGES;

  hipMemsetAsync(cnt, 0, N_NODES * sizeof(int), stream);
  hist_kernel<<<(N_EDGES + 255) / 256, 256, 0, stream>>>(dst, cnt);
  bscan1<<<SCAN_NB, 256, 0, stream>>>(cnt, rowp, bsums);
  bscan2<<<1, 64, 0, stream>>>(bsums, rowp);
  bscan3<<<SCAN_NB, 256, 0, stream>>>(rowp, fill, bsums);
  scatter_kernel<<<(N_EDGES + 255) / 256, 256, 0, stream>>>(src, dst, fill, col);
  prep_w_kernel<<<(2 * 128 * 256 + 8 * 256 * 256 + 255) / 256, 256, 0, stream>>>(lw, gw, linT, gcnT);

  dim3 lg((N_NODES + 255) / 256, 4);
  lin_mfma_kernel<<<lg, 256, 0, stream>>>(x0, x1, linT, lb, h0);

  // layers: fused agg+gemm; h ping-pongs hb <-> xb (gather reads prev buffer,
  // kernel-launch boundary is the producer/consumer barrier)
  const short* hin = h0;
  for (int l = 0; l < NLAYER; ++l) {
    float beta = logf(0.5f / (float)(l + 1) + 1.0f);
    short* hout = (l & 1) ? xb : hb;
    layer_fused<<<(N_NODES + 63) / 64, 512, 0, stream>>>(hin, h0, rowp, col,
                                                         gcnT + (size_t)l * CHN * CHN,
                                                         hout, beta);
    hin = hout;
  }
  out_kernel<<<N_NODES / 32, 256, 0, stream>>>(hin, ow, ob, outp);
}